// Round 1
// baseline (504.648 us; speedup 1.0000x reference)
//
#include <hip/hip_runtime.h>
#include <cstdint>

typedef __attribute__((ext_vector_type(4))) float f32x4;
typedef __attribute__((ext_vector_type(8))) __bf16 bf16x8;
typedef __attribute__((ext_vector_type(8))) unsigned short u16x8;
typedef __attribute__((ext_vector_type(4))) unsigned short u16x4;
typedef __attribute__((ext_vector_type(4))) float fvec4;

#define DEV __device__ __forceinline__
#define MFMA16(a, b, c) __builtin_amdgcn_mfma_f32_16x16x32_bf16((a), (b), (c), 0, 0, 0)

// RNE float -> bf16
DEV unsigned short f2bf(float f) {
  union { float f; uint32_t u; } c; c.f = f;
  uint32_t u = c.u;
  return (unsigned short)((u + 0x7FFFu + ((u >> 16) & 1u)) >> 16);
}

// async global->LDS, 16B per lane; LDS dest = wave-uniform base + lane*16
DEV void gll16(const void* g, void* l) {
  __builtin_amdgcn_global_load_lds(
      (const __attribute__((address_space(1))) void*)(uintptr_t)g,
      (__attribute__((address_space(3))) void*)(uint32_t)(uintptr_t)l,
      16, 0, 0);
}

// ---------------- elementwise fp32 -> bf16 (8M elems, 4/thread) ----------------
__global__ void cvt_bf16(const float* __restrict__ src, unsigned short* __restrict__ dst) {
  int i = (blockIdx.x * 256 + threadIdx.x) * 4;
  fvec4 v = *(const fvec4*)(src + i);
  u16x4 o;
  o[0] = f2bf(v[0]); o[1] = f2bf(v[1]); o[2] = f2bf(v[2]); o[3] = f2bf(v[3]);
  *(u16x4*)(dst + i) = o;
}

// ---------------- W [K][N] fp32 -> WT [N][K] bf16 ----------------
__global__ void transpose_cvt(const float* __restrict__ W, unsigned short* __restrict__ WT) {
  __shared__ float t[32][33];
  int n0 = blockIdx.x * 32, k0 = blockIdx.y * 32;
  int x = threadIdx.x, y = threadIdx.y;  // block (32,8)
  #pragma unroll
  for (int i = 0; i < 32; i += 8)
    t[y + i][x] = W[(size_t)(k0 + y + i) * 2048 + n0 + x];
  __syncthreads();
  #pragma unroll
  for (int i = 0; i < 32; i += 8)
    WT[(size_t)(n0 + y + i) * 2048 + k0 + x] = f2bf(t[x][y + i]);
}

// ---------------- 128x128-tile GEMM: C = A @ Bt^T + bias ----------------
// A [4096][2048] bf16 row-major, Bt [2048][2048] bf16 (N-major, i.e. W^T).
// LDS tiles As/Bs [128][64] bf16, column-group XOR-swizzled by row&7 to kill
// the 16-lane same-bank pattern (m98: ~16 conflict cyc per ds_read_b128).
template <bool SPLIT_HEAD>
__global__ __launch_bounds__(256, 2) void gemm128(
    const unsigned short* __restrict__ A,
    const unsigned short* __restrict__ Bt,
    const float* __restrict__ bias,
    void* __restrict__ outp) {
  __shared__ unsigned short As[128 * 64];
  __shared__ unsigned short Bs[128 * 64];
  const int n0 = blockIdx.x * 128, m0 = blockIdx.y * 128;
  const int tid = threadIdx.x;
  const int wave = tid >> 6, lid = tid & 63;
  const int l16 = lid & 15, lq = lid >> 4;
  const int wm = (wave >> 1) * 64, wn = (wave & 1) * 64;

  const int srow = lid >> 3;          // 0..7 (row within 8-row group)
  const int sgrp = (lid & 7) ^ srow;  // swizzled global 8-elem column group

  f32x4 acc[4][4] = {};

  for (int k0 = 0; k0 < 2048; k0 += 64) {
    #pragma unroll
    for (int i = 0; i < 4; ++i) {
      const int t = wave * 4 + i;
      const int r = t * 8 + srow;
      gll16(A + (size_t)(m0 + r) * 2048 + k0 + sgrp * 8, (char*)As + t * 1024 + lid * 16);
      gll16(Bt + (size_t)(n0 + r) * 2048 + k0 + sgrp * 8, (char*)Bs + t * 1024 + lid * 16);
    }
    __syncthreads();
    #pragma unroll
    for (int kk = 0; kk < 2; ++kk) {
      const int G = kk * 4 + lq;  // k-group 0..7
      bf16x8 af[4], bfr[4];
      #pragma unroll
      for (int i = 0; i < 4; ++i)
        af[i] = *(const bf16x8*)(As + (wm + i * 16 + l16) * 64 + ((G ^ (l16 & 7)) << 3));
      #pragma unroll
      for (int j = 0; j < 4; ++j)
        bfr[j] = *(const bf16x8*)(Bs + (wn + j * 16 + l16) * 64 + ((G ^ (l16 & 7)) << 3));
      #pragma unroll
      for (int i = 0; i < 4; ++i)
        #pragma unroll
        for (int j = 0; j < 4; ++j)
          acc[i][j] = MFMA16(af[i], bfr[j], acc[i][j]);
    }
    __syncthreads();
  }

  // epilogue: C/D layout col=lane&15, row=(lane>>4)*4+reg (m89-verified)
  #pragma unroll
  for (int j = 0; j < 4; ++j) {
    const int c = n0 + wn + j * 16 + l16;
    const float bv = bias[c];
    #pragma unroll
    for (int i = 0; i < 4; ++i) {
      #pragma unroll
      for (int r = 0; r < 4; ++r) {
        const int row = m0 + wm + i * 16 + lq * 4 + r;
        const float val = acc[i][j][r] + bv;
        if (SPLIT_HEAD) {
          const int b = row >> 11, s = row & 2047;
          const int h = c >> 7, d = c & 127;
          ((unsigned short*)outp)[(size_t)((b * 16 + h) * 2048 + s) * 128 + d] = f2bf(val);
        } else {
          ((float*)outp)[(size_t)row * 2048 + c] = val;
        }
      }
    }
  }
}

// ---------------- flash attention, causal, bf16 ----------------
// grid (S/128, B*NH), 256 threads. Q-frags in registers; K-tile (64 rows)
// via global_load_lds; V staged transposed; P via LDS (C-layout -> A-layout).
constexpr float SC = 0.08838834764831845f * 1.4426950408889634f;  // 1/sqrt(DH) * log2(e)

__global__ __launch_bounds__(256, 2) void attn(
    const unsigned short* __restrict__ Q,
    const unsigned short* __restrict__ K,
    const unsigned short* __restrict__ V,
    unsigned short* __restrict__ ctx) {
  __shared__ unsigned short Ks[64 * 128];   // [kr][d], grp ^ (kr&15)
  __shared__ unsigned short Vts[128 * 64];  // [d][kr], grp ^ (d&7)
  __shared__ unsigned short Ps[128 * 64];   // [q][kr], grp ^ (q&7)

  const int q0 = blockIdx.x * 128;
  const int bh = blockIdx.y;
  const unsigned short* Qh = Q + (size_t)bh * 2048 * 128;
  const unsigned short* Kh = K + (size_t)bh * 2048 * 128;
  const unsigned short* Vh = V + (size_t)bh * 2048 * 128;

  const int tid = threadIdx.x;
  const int wave = tid >> 6, lid = tid & 63;
  const int l16 = lid & 15, lq = lid >> 4;
  const int wq = wave * 32;  // wave owns q rows [wq, wq+32)

  bf16x8 qf[2][4];
  #pragma unroll
  for (int i = 0; i < 2; ++i)
    #pragma unroll
    for (int kc = 0; kc < 4; ++kc)
      qf[i][kc] = *(const bf16x8*)(Qh + (size_t)(q0 + wq + i * 16 + l16) * 128 + kc * 32 + lq * 8);

  float mrow[2][4], lrow[2][4];
  f32x4 acc_o[2][8] = {};
  #pragma unroll
  for (int i = 0; i < 2; ++i)
    #pragma unroll
    for (int r = 0; r < 4; ++r) { mrow[i][r] = -1e30f; lrow[i][r] = 0.f; }

  const int ntiles = q0 / 64 + 2;  // causal: only k0 < q0+128
  for (int jt = 0; jt < ntiles; ++jt) {
    const int k0 = jt * 64;
    #pragma unroll
    for (int ii = 0; ii < 4; ++ii) {
      const int t = wave * 4 + ii;
      const int r = t * 4 + lq;             // k-row 0..63
      const int g = (lid & 15) ^ (r & 15);  // swizzled source d-group
      gll16(Kh + (size_t)(k0 + r) * 128 + g * 8, (char*)Ks + t * 1024 + lid * 16);
    }
    {  // V transpose staging
      const int kr = tid >> 2, db = (tid & 3) * 32;
      #pragma unroll
      for (int u = 0; u < 4; ++u) {
        u16x8 v = *(const u16x8*)(Vh + (size_t)(k0 + kr) * 128 + db + u * 8);
        #pragma unroll
        for (int e = 0; e < 8; ++e) {
          const int d = db + u * 8 + e;
          Vts[d * 64 + ((((kr >> 3) ^ (d & 7)) << 3) | (kr & 7))] = v[e];
        }
      }
    }
    __syncthreads();

    // S = Q K^T  (M=q, N=k-col, Kdim=d)
    f32x4 sacc[2][4] = {};
    #pragma unroll
    for (int kc = 0; kc < 4; ++kc) {
      #pragma unroll
      for (int jn = 0; jn < 4; ++jn) {
        bf16x8 kf = *(const bf16x8*)(Ks + (jn * 16 + l16) * 128 + (((kc * 4 + lq) ^ l16) << 3));
        sacc[0][jn] = MFMA16(qf[0][kc], kf, sacc[0][jn]);
        sacc[1][jn] = MFMA16(qf[1][kc], kf, sacc[1][jn]);
      }
    }

    // online softmax (exp2 domain); rows replicated across 16-lane groups
    #pragma unroll
    for (int i = 0; i < 2; ++i) {
      #pragma unroll
      for (int r = 0; r < 4; ++r) {
        const int qrow = q0 + wq + i * 16 + lq * 4 + r;
        float sv[4];
        float tmax = -1e30f;
        #pragma unroll
        for (int jn = 0; jn < 4; ++jn) {
          float s = sacc[i][jn][r] * SC;
          if (k0 + jn * 16 + l16 > qrow) s = -1e30f;  // causal
          sv[jn] = s;
          tmax = fmaxf(tmax, s);
        }
        tmax = fmaxf(tmax, __shfl_xor(tmax, 1));
        tmax = fmaxf(tmax, __shfl_xor(tmax, 2));
        tmax = fmaxf(tmax, __shfl_xor(tmax, 4));
        tmax = fmaxf(tmax, __shfl_xor(tmax, 8));
        const float mnew = fmaxf(mrow[i][r], tmax);
        const float alpha = exp2f(mrow[i][r] - mnew);
        mrow[i][r] = mnew;
        float psum = 0.f;
        const int ql = wq + i * 16 + lq * 4 + r;  // local q row
        #pragma unroll
        for (int jn = 0; jn < 4; ++jn) {
          const float p = exp2f(sv[jn] - mnew);
          psum += p;
          const int grp = (jn * 2 + (l16 >> 3)) ^ (ql & 7);
          Ps[ql * 64 + (grp << 3) + (l16 & 7)] = f2bf(p);
        }
        psum += __shfl_xor(psum, 1);
        psum += __shfl_xor(psum, 2);
        psum += __shfl_xor(psum, 4);
        psum += __shfl_xor(psum, 8);
        lrow[i][r] = lrow[i][r] * alpha + psum;
        #pragma unroll
        for (int dj = 0; dj < 8; ++dj) acc_o[i][dj][r] *= alpha;
      }
    }
    __syncthreads();

    // O += P V  (M=q, N=d, Kdim=k)
    #pragma unroll
    for (int kc = 0; kc < 2; ++kc) {
      const int G = kc * 4 + lq;
      bf16x8 pf0 = *(const bf16x8*)(Ps + (wq + l16) * 64 + ((G ^ (l16 & 7)) << 3));
      bf16x8 pf1 = *(const bf16x8*)(Ps + (wq + 16 + l16) * 64 + ((G ^ (l16 & 7)) << 3));
      #pragma unroll
      for (int dj = 0; dj < 8; ++dj) {
        bf16x8 vf = *(const bf16x8*)(Vts + (dj * 16 + l16) * 64 + ((G ^ (l16 & 7)) << 3));
        acc_o[0][dj] = MFMA16(pf0, vf, acc_o[0][dj]);
        acc_o[1][dj] = MFMA16(pf1, vf, acc_o[1][dj]);
      }
    }
    __syncthreads();
  }

  // epilogue: ctx[b][s][h*128+d] bf16
  const int b = bh >> 4, h = bh & 15;
  #pragma unroll
  for (int i = 0; i < 2; ++i) {
    #pragma unroll
    for (int r = 0; r < 4; ++r) {
      const int s = q0 + wq + i * 16 + lq * 4 + r;
      const float inv = 1.f / lrow[i][r];
      const size_t base = ((size_t)(b * 2048 + s)) * 2048 + h * 128;
      #pragma unroll
      for (int dj = 0; dj < 8; ++dj)
        ctx[base + dj * 16 + l16] = f2bf(acc_o[i][dj][r] * inv);
    }
  }
}

// ---------------- launch ----------------
extern "C" void kernel_launch(void* const* d_in, const int* in_sizes, int n_in,
                              void* d_out, int out_size, void* d_ws, size_t ws_size,
                              hipStream_t stream) {
  const float* hs = (const float*)d_in[0];
  const float* Wq = (const float*)d_in[1];
  const float* bq = (const float*)d_in[2];
  const float* Wk = (const float*)d_in[3];
  const float* bk = (const float*)d_in[4];
  const float* Wv = (const float*)d_in[5];
  const float* bv = (const float*)d_in[6];
  const float* Wo = (const float*)d_in[7];
  const float* bo = (const float*)d_in[8];
  // d_in[9] = causal_mask: standard causal mask, computed analytically in attn.
  float* out = (float*)d_out;

  char* ws = (char*)d_ws;
  unsigned short* hsb = (unsigned short*)(ws);              // 16 MB [4096][2048]
  unsigned short* wqt = (unsigned short*)(ws + (16 << 20)); //  8 MB [2048][2048]
  unsigned short* wkt = (unsigned short*)(ws + (24 << 20));
  unsigned short* wvt = (unsigned short*)(ws + (32 << 20));
  unsigned short* wot = (unsigned short*)(ws + (40 << 20));
  unsigned short* Qb  = (unsigned short*)(ws + (48 << 20)); // 16 MB [B*NH][S][DH]
  unsigned short* Kb  = (unsigned short*)(ws + (64 << 20));
  unsigned short* Vb  = (unsigned short*)(ws + (80 << 20));
  unsigned short* ctx = (unsigned short*)(ws + (96 << 20)); // 16 MB [4096][2048]

  cvt_bf16<<<dim3(8192), dim3(256), 0, stream>>>(hs, hsb);
  dim3 tb(32, 8);
  transpose_cvt<<<dim3(64, 64), tb, 0, stream>>>(Wq, wqt);
  transpose_cvt<<<dim3(64, 64), tb, 0, stream>>>(Wk, wkt);
  transpose_cvt<<<dim3(64, 64), tb, 0, stream>>>(Wv, wvt);
  transpose_cvt<<<dim3(64, 64), tb, 0, stream>>>(Wo, wot);

  gemm128<true><<<dim3(16, 32), 256, 0, stream>>>(hsb, wqt, bq, (void*)Qb);
  gemm128<true><<<dim3(16, 32), 256, 0, stream>>>(hsb, wkt, bk, (void*)Kb);
  gemm128<true><<<dim3(16, 32), 256, 0, stream>>>(hsb, wvt, bv, (void*)Vb);

  attn<<<dim3(16, 32), 256, 0, stream>>>(Qb, Kb, Vb, ctx);

  gemm128<false><<<dim3(16, 32), 256, 0, stream>>>(ctx, wot, bo, (void*)out);
}

// Round 2
// 455.776 us; speedup vs baseline: 1.1072x; 1.1072x over previous
//
#include <hip/hip_runtime.h>
#include <cstdint>

typedef __attribute__((ext_vector_type(4))) float f32x4;
typedef __attribute__((ext_vector_type(8))) __bf16 bf16x8;
typedef __attribute__((ext_vector_type(4))) unsigned short u16x4;
typedef __attribute__((ext_vector_type(4))) float fvec4;

#define DEV __device__ __forceinline__
#define MFMA16(a, b, c) __builtin_amdgcn_mfma_f32_16x16x32_bf16((a), (b), (c), 0, 0, 0)

// RNE float -> bf16
DEV unsigned short f2bf(float f) {
  union { float f; uint32_t u; } c; c.f = f;
  uint32_t u = c.u;
  return (unsigned short)((u + 0x7FFFu + ((u >> 16) & 1u)) >> 16);
}

// async global->LDS, 16B/lane; LDS dest = wave-uniform base + lane*16
DEV void gll16(const void* g, void* l) {
  __builtin_amdgcn_global_load_lds(
      (const __attribute__((address_space(1))) void*)(uintptr_t)g,
      (__attribute__((address_space(3))) void*)(uint32_t)(uintptr_t)l,
      16, 0, 0);
}

// ---------------- elementwise fp32 -> bf16 ----------------
__global__ void cvt_bf16(const float* __restrict__ src, unsigned short* __restrict__ dst) {
  int i = (blockIdx.x * 256 + threadIdx.x) * 4;
  fvec4 v = *(const fvec4*)(src + i);
  u16x4 o;
  o[0] = f2bf(v[0]); o[1] = f2bf(v[1]); o[2] = f2bf(v[2]); o[3] = f2bf(v[3]);
  *(u16x4*)(dst + i) = o;
}

// ---------------- W [K][N] fp32 -> WT [N][K] bf16 ----------------
__global__ void transpose_cvt(const float* __restrict__ W, unsigned short* __restrict__ WT) {
  __shared__ float t[32][33];
  int n0 = blockIdx.x * 32, k0 = blockIdx.y * 32;
  int x = threadIdx.x, y = threadIdx.y;  // block (32,8)
  #pragma unroll
  for (int i = 0; i < 32; i += 8)
    t[y + i][x] = W[(size_t)(k0 + y + i) * 2048 + n0 + x];
  __syncthreads();
  #pragma unroll
  for (int i = 0; i < 32; i += 8)
    WT[(size_t)(n0 + y + i) * 2048 + k0 + x] = f2bf(t[x][y + i]);
}

// ---------------- 128x128-tile GEMM ----------------
// MODE 0: C = A@Bt^T + b0 -> fp32 out o0 [4096][2048]
// MODE 1: fused QKV over N=6144; Q/K split-head bf16 [bh][s][d]; V written
//         TRANSPOSED per head: Vt[bh][d][s]  (kills the attn V-transpose)
template <int MODE>
__global__ __launch_bounds__(256, 2) void gemm128(
    const unsigned short* __restrict__ A,
    const unsigned short* __restrict__ Bt,
    const float* __restrict__ b0, const float* __restrict__ b1,
    const float* __restrict__ b2,
    void* __restrict__ o0, void* __restrict__ o1, void* __restrict__ o2) {
  __shared__ unsigned short As[128 * 64];
  __shared__ unsigned short Bs[128 * 64];
  const int n0 = blockIdx.x * 128, m0 = blockIdx.y * 128;
  const int tid = threadIdx.x;
  const int wave = tid >> 6, lid = tid & 63;
  const int l16 = lid & 15, lq = lid >> 4;
  const int wm = (wave >> 1) * 64, wn = (wave & 1) * 64;

  const int srow = lid >> 3;          // 0..7
  const int sgrp = (lid & 7) ^ srow;  // swizzled global 8-elem column group

  f32x4 acc[4][4] = {};

  for (int k0 = 0; k0 < 2048; k0 += 64) {
    #pragma unroll
    for (int i = 0; i < 4; ++i) {
      const int t = wave * 4 + i;
      const int r = t * 8 + srow;
      gll16(A + (size_t)(m0 + r) * 2048 + k0 + sgrp * 8, (char*)As + t * 1024 + lid * 16);
      gll16(Bt + (size_t)(n0 + r) * 2048 + k0 + sgrp * 8, (char*)Bs + t * 1024 + lid * 16);
    }
    __syncthreads();
    #pragma unroll
    for (int kk = 0; kk < 2; ++kk) {
      const int G = kk * 4 + lq;
      bf16x8 af[4], bfr[4];
      #pragma unroll
      for (int i = 0; i < 4; ++i)
        af[i] = *(const bf16x8*)(As + (wm + i * 16 + l16) * 64 + ((G ^ (l16 & 7)) << 3));
      #pragma unroll
      for (int j = 0; j < 4; ++j)
        bfr[j] = *(const bf16x8*)(Bs + (wn + j * 16 + l16) * 64 + ((G ^ (l16 & 7)) << 3));
      #pragma unroll
      for (int i = 0; i < 4; ++i)
        #pragma unroll
        for (int j = 0; j < 4; ++j)
          acc[i][j] = MFMA16(af[i], bfr[j], acc[i][j]);
    }
    __syncthreads();
  }

  // epilogue: C/D layout col=lane&15, row=(lane>>4)*4+reg
  #pragma unroll
  for (int j = 0; j < 4; ++j) {
    const int c = n0 + wn + j * 16 + l16;
    if (MODE == 1) {
      const int which = c >> 11;           // 0=Q 1=K 2=V (wave-uniform)
      const int hd = c & 2047;
      const int h = hd >> 7, d = hd & 127;
      const float* bp = which == 0 ? b0 : which == 1 ? b1 : b2;
      const float bv = bp[hd];
      #pragma unroll
      for (int i = 0; i < 4; ++i) {
        #pragma unroll
        for (int r = 0; r < 4; ++r) {
          const int row = m0 + wm + i * 16 + lq * 4 + r;
          const int bb = row >> 11, s = row & 2047;
          const unsigned short us = f2bf(acc[i][j][r] + bv);
          const int bh = bb * 16 + h;
          if (which == 0)
            ((unsigned short*)o0)[(size_t)(bh * 2048 + s) * 128 + d] = us;
          else if (which == 1)
            ((unsigned short*)o1)[(size_t)(bh * 2048 + s) * 128 + d] = us;
          else
            ((unsigned short*)o2)[((size_t)(bh * 128 + d)) * 2048 + s] = us;
        }
      }
    } else {
      const float bv = b0[c];
      #pragma unroll
      for (int i = 0; i < 4; ++i)
        #pragma unroll
        for (int r = 0; r < 4; ++r) {
          const int row = m0 + wm + i * 16 + lq * 4 + r;
          ((float*)o0)[(size_t)row * 2048 + c] = acc[i][j][r] + bv;
        }
    }
  }
}

// ---------------- flash attention, causal, paired 64-row q-tiles ----------------
// grid (16, 32), 256 thr. Block x does q-tiles x and 31-x -> uniform 33 k-tiles.
// V arrives pre-transposed Vt[bh][d][s]. Mask applied only on diagonal tile.
constexpr float SC = 0.08838834764831845f * 1.4426950408889634f;  // rsqrt(DH)*log2(e)

__global__ __launch_bounds__(256, 2) void attn(
    const unsigned short* __restrict__ Q,
    const unsigned short* __restrict__ K,
    const unsigned short* __restrict__ Vt,
    unsigned short* __restrict__ ctx) {
  __shared__ unsigned short Ks[64 * 128];   // [kr][dgrp^(kr&15)]
  __shared__ unsigned short Vts[128 * 64];  // [d][kgrp^(d&7)]
  __shared__ unsigned short Ps[64 * 64];    // [q][kgrp^(q&7)]

  const int bh = blockIdx.y;
  const int b = bh >> 4, h = bh & 15;
  const unsigned short* Qh = Q + (size_t)bh * 2048 * 128;
  const unsigned short* Kh = K + (size_t)bh * 2048 * 128;
  const unsigned short* Vth = Vt + (size_t)bh * 128 * 2048;

  const int tid = threadIdx.x;
  const int wave = tid >> 6, lid = tid & 63;
  const int l16 = lid & 15, lq = lid >> 4;
  const int wq = wave * 16;  // wave owns q rows [wq, wq+16)

  for (int phase = 0; phase < 2; ++phase) {
    const int jq = phase == 0 ? (int)blockIdx.x : 31 - (int)blockIdx.x;
    const int q0 = jq * 64;

    bf16x8 qf[4];
    #pragma unroll
    for (int kc = 0; kc < 4; ++kc)
      qf[kc] = *(const bf16x8*)(Qh + (size_t)(q0 + wq + l16) * 128 + kc * 32 + lq * 8);

    float mrow[4], lrow[4];
    f32x4 acc_o[8];
    #pragma unroll
    for (int r = 0; r < 4; ++r) { mrow[r] = -1e30f; lrow[r] = 0.f; }
    #pragma unroll
    for (int dj = 0; dj < 8; ++dj) acc_o[dj] = (f32x4){0.f, 0.f, 0.f, 0.f};

    const int ntiles = jq + 1;
    for (int jt = 0; jt < ntiles; ++jt) {
      const int k0 = jt * 64;
      #pragma unroll
      for (int ii = 0; ii < 4; ++ii) {  // K tile: 16 KB
        const int t = wave * 4 + ii;
        const int r = t * 4 + lq;
        const int g = l16 ^ (r & 15);
        gll16(Kh + (size_t)(k0 + r) * 128 + g * 8, (char*)Ks + t * 1024 + lid * 16);
      }
      #pragma unroll
      for (int ii = 0; ii < 4; ++ii) {  // Vt tile: 16 KB, already [d][s]
        const int t = wave * 4 + ii;
        const int d = t * 8 + (lid >> 3);
        const int g = (lid & 7) ^ (d & 7);
        gll16(Vth + (size_t)d * 2048 + k0 + g * 8, (char*)Vts + t * 1024 + lid * 16);
      }
      __syncthreads();

      // S = Q K^T
      f32x4 sacc[4] = {};
      #pragma unroll
      for (int kc = 0; kc < 4; ++kc) {
        #pragma unroll
        for (int jn = 0; jn < 4; ++jn) {
          bf16x8 kf = *(const bf16x8*)(Ks + (jn * 16 + l16) * 128 + (((kc * 4 + lq) ^ l16) << 3));
          sacc[jn] = MFMA16(qf[kc], kf, sacc[jn]);
        }
      }

      const bool diag = (jt == ntiles - 1);
      #pragma unroll
      for (int r = 0; r < 4; ++r) {
        const int ql = wq + lq * 4 + r;
        const int qrow = q0 + ql;
        float sv[4];
        float tmax = -1e30f;
        #pragma unroll
        for (int jn = 0; jn < 4; ++jn) {
          float s = sacc[jn][r] * SC;
          if (diag && (k0 + jn * 16 + l16 > qrow)) s = -1e30f;
          sv[jn] = s;
          tmax = fmaxf(tmax, s);
        }
        tmax = fmaxf(tmax, __shfl_xor(tmax, 1));
        tmax = fmaxf(tmax, __shfl_xor(tmax, 2));
        tmax = fmaxf(tmax, __shfl_xor(tmax, 4));
        tmax = fmaxf(tmax, __shfl_xor(tmax, 8));
        const float mnew = fmaxf(mrow[r], tmax);
        const float alpha = exp2f(mrow[r] - mnew);
        mrow[r] = mnew;
        float psum = 0.f;
        #pragma unroll
        for (int jn = 0; jn < 4; ++jn) {
          const float p = exp2f(sv[jn] - mnew);
          psum += p;
          const int sg = (jn * 2 + (l16 >> 3)) ^ (ql & 7);
          Ps[ql * 64 + (sg << 3) + (l16 & 7)] = f2bf(p);
        }
        psum += __shfl_xor(psum, 1);
        psum += __shfl_xor(psum, 2);
        psum += __shfl_xor(psum, 4);
        psum += __shfl_xor(psum, 8);
        lrow[r] = lrow[r] * alpha + psum;
        #pragma unroll
        for (int dj = 0; dj < 8; ++dj) acc_o[dj][r] *= alpha;
      }
      __syncthreads();

      // O += P V
      #pragma unroll
      for (int kc = 0; kc < 2; ++kc) {
        const int G = kc * 4 + lq;
        bf16x8 pf = *(const bf16x8*)(Ps + (wq + l16) * 64 + ((G ^ (l16 & 7)) << 3));
        #pragma unroll
        for (int dj = 0; dj < 8; ++dj) {
          bf16x8 vf = *(const bf16x8*)(Vts + (dj * 16 + l16) * 64 + ((G ^ (l16 & 7)) << 3));
          acc_o[dj] = MFMA16(pf, vf, acc_o[dj]);
        }
      }
      __syncthreads();
    }

    // epilogue: ctx[b][s][h*128+d]
    #pragma unroll
    for (int r = 0; r < 4; ++r) {
      const int s = q0 + wq + lq * 4 + r;
      const float inv = 1.f / lrow[r];
      const size_t base = ((size_t)(b * 2048 + s)) * 2048 + h * 128;
      #pragma unroll
      for (int dj = 0; dj < 8; ++dj)
        ctx[base + dj * 16 + l16] = f2bf(acc_o[dj][r] * inv);
    }
  }
}

// ---------------- launch ----------------
extern "C" void kernel_launch(void* const* d_in, const int* in_sizes, int n_in,
                              void* d_out, int out_size, void* d_ws, size_t ws_size,
                              hipStream_t stream) {
  const float* hs = (const float*)d_in[0];
  const float* Wq = (const float*)d_in[1];
  const float* bq = (const float*)d_in[2];
  const float* Wk = (const float*)d_in[3];
  const float* bk = (const float*)d_in[4];
  const float* Wv = (const float*)d_in[5];
  const float* bv = (const float*)d_in[6];
  const float* Wo = (const float*)d_in[7];
  const float* bo = (const float*)d_in[8];
  // d_in[9] = causal_mask (standard causal; computed analytically in attn)
  float* out = (float*)d_out;

  char* ws = (char*)d_ws;
  unsigned short* hsb   = (unsigned short*)(ws);              // 16 MB [4096][2048]
  unsigned short* wqkvt = (unsigned short*)(ws + (16 << 20)); // 24 MB [6144][2048]
  unsigned short* wot   = (unsigned short*)(ws + (40 << 20)); //  8 MB
  unsigned short* Qb    = (unsigned short*)(ws + (48 << 20)); // 16 MB [bh][s][d]
  unsigned short* Kb    = (unsigned short*)(ws + (64 << 20)); // 16 MB [bh][s][d]
  unsigned short* Vtb   = (unsigned short*)(ws + (80 << 20)); // 16 MB [bh][d][s]
  unsigned short* ctx   = (unsigned short*)(ws + (96 << 20)); // 16 MB [4096][2048]

  cvt_bf16<<<dim3(8192), dim3(256), 0, stream>>>(hs, hsb);
  dim3 tb(32, 8);
  transpose_cvt<<<dim3(64, 64), tb, 0, stream>>>(Wq, wqkvt);
  transpose_cvt<<<dim3(64, 64), tb, 0, stream>>>(Wk, wqkvt + 2048 * 2048);
  transpose_cvt<<<dim3(64, 64), tb, 0, stream>>>(Wv, wqkvt + 2 * 2048 * 2048);
  transpose_cvt<<<dim3(64, 64), tb, 0, stream>>>(Wo, wot);

  gemm128<1><<<dim3(48, 32), 256, 0, stream>>>(hsb, wqkvt, bq, bk, bv,
                                               (void*)Qb, (void*)Kb, (void*)Vtb);
  attn<<<dim3(16, 32), 256, 0, stream>>>(Qb, Kb, Vtb, ctx);
  gemm128<0><<<dim3(16, 32), 256, 0, stream>>>(ctx, wot, bo, nullptr, nullptr,
                                               (void*)out, nullptr, nullptr);
}

// Round 3
// 410.503 us; speedup vs baseline: 1.2293x; 1.1103x over previous
//
#include <hip/hip_runtime.h>
#include <cstdint>

typedef __attribute__((ext_vector_type(4))) float f32x4;
typedef __attribute__((ext_vector_type(8))) __bf16 bf16x8;
typedef __attribute__((ext_vector_type(4))) unsigned short u16x4;
typedef __attribute__((ext_vector_type(4))) float fvec4;

#define DEV __device__ __forceinline__
#define MFMA16(a, b, c) __builtin_amdgcn_mfma_f32_16x16x32_bf16((a), (b), (c), 0, 0, 0)

// RNE float -> bf16
DEV unsigned short f2bf(float f) {
  union { float f; uint32_t u; } c; c.f = f;
  uint32_t u = c.u;
  return (unsigned short)((u + 0x7FFFu + ((u >> 16) & 1u)) >> 16);
}

// async global->LDS, 16B/lane; LDS dest = wave-uniform base + lane*16
DEV void gll16(const void* g, void* l) {
  __builtin_amdgcn_global_load_lds(
      (const __attribute__((address_space(1))) void*)(uintptr_t)g,
      (__attribute__((address_space(3))) void*)(uint32_t)(uintptr_t)l,
      16, 0, 0);
}

// ---------------- elementwise fp32 -> bf16 ----------------
__global__ void cvt_bf16(const float* __restrict__ src, unsigned short* __restrict__ dst) {
  int i = (blockIdx.x * 256 + threadIdx.x) * 4;
  fvec4 v = *(const fvec4*)(src + i);
  u16x4 o;
  o[0] = f2bf(v[0]); o[1] = f2bf(v[1]); o[2] = f2bf(v[2]); o[3] = f2bf(v[3]);
  *(u16x4*)(dst + i) = o;
}

// ---------------- 4x fused: W [K][N] fp32 -> WT [N][K] bf16 ----------------
__global__ void transpose_cvt4(const float* __restrict__ W0, const float* __restrict__ W1,
                               const float* __restrict__ W2, const float* __restrict__ W3,
                               unsigned short* __restrict__ Dqkv, unsigned short* __restrict__ Do) {
  __shared__ float t[32][33];
  const float* W = blockIdx.z == 0 ? W0 : blockIdx.z == 1 ? W1 : blockIdx.z == 2 ? W2 : W3;
  unsigned short* WT = blockIdx.z < 3 ? Dqkv + (size_t)blockIdx.z * 2048 * 2048 : Do;
  int n0 = blockIdx.x * 32, k0 = blockIdx.y * 32;
  int x = threadIdx.x, y = threadIdx.y;  // block (32,8)
  #pragma unroll
  for (int i = 0; i < 32; i += 8)
    t[y + i][x] = W[(size_t)(k0 + y + i) * 2048 + n0 + x];
  __syncthreads();
  #pragma unroll
  for (int i = 0; i < 32; i += 8)
    WT[(size_t)(n0 + y + i) * 2048 + k0 + x] = f2bf(t[x][y + i]);
}

// softmax scale folded into Q (exp2 domain): rsqrt(DH)*log2(e)
constexpr float QSC = 0.08838834764831845f * 1.4426950408889634f;

// ---------------- 128x128-tile GEMM ----------------
// MODE 0: C = A@Bt^T + b0 -> fp32 out o0 [4096][2048]
// MODE 1: fused QKV over N=6144; Q (scaled by QSC) / K split-head bf16
//         [bh][s][d]; V transposed per head: Vt[bh][d][s] (packed stores)
template <int MODE>
__global__ __launch_bounds__(256, 2) void gemm128(
    const unsigned short* __restrict__ A,
    const unsigned short* __restrict__ Bt,
    const float* __restrict__ b0, const float* __restrict__ b1,
    const float* __restrict__ b2,
    void* __restrict__ o0, void* __restrict__ o1, void* __restrict__ o2) {
  __shared__ unsigned short As[128 * 64];
  __shared__ unsigned short Bs[128 * 64];
  const int n0 = blockIdx.x * 128, m0 = blockIdx.y * 128;
  const int tid = threadIdx.x;
  const int wave = tid >> 6, lid = tid & 63;
  const int l16 = lid & 15, lq = lid >> 4;
  const int wm = (wave >> 1) * 64, wn = (wave & 1) * 64;

  const int srow = lid >> 3;          // 0..7
  const int sgrp = (lid & 7) ^ srow;  // swizzled global 8-elem column group

  f32x4 acc[4][4] = {};

  for (int k0 = 0; k0 < 2048; k0 += 64) {
    #pragma unroll
    for (int i = 0; i < 4; ++i) {
      const int t = wave * 4 + i;
      const int r = t * 8 + srow;
      gll16(A + (size_t)(m0 + r) * 2048 + k0 + sgrp * 8, (char*)As + t * 1024 + lid * 16);
      gll16(Bt + (size_t)(n0 + r) * 2048 + k0 + sgrp * 8, (char*)Bs + t * 1024 + lid * 16);
    }
    __syncthreads();
    #pragma unroll
    for (int kk = 0; kk < 2; ++kk) {
      const int G = kk * 4 + lq;
      bf16x8 af[4], bfr[4];
      #pragma unroll
      for (int i = 0; i < 4; ++i)
        af[i] = *(const bf16x8*)(As + (wm + i * 16 + l16) * 64 + ((G ^ (l16 & 7)) << 3));
      #pragma unroll
      for (int j = 0; j < 4; ++j)
        bfr[j] = *(const bf16x8*)(Bs + (wn + j * 16 + l16) * 64 + ((G ^ (l16 & 7)) << 3));
      #pragma unroll
      for (int i = 0; i < 4; ++i)
        #pragma unroll
        for (int j = 0; j < 4; ++j)
          acc[i][j] = MFMA16(af[i], bfr[j], acc[i][j]);
    }
    __syncthreads();
  }

  // epilogue: C/D layout col=lane&15, row=(lane>>4)*4+reg
  #pragma unroll
  for (int j = 0; j < 4; ++j) {
    const int c = n0 + wn + j * 16 + l16;
    if (MODE == 1) {
      const int which = c >> 11;  // 0=Q 1=K 2=V (uniform per 16-lane group)
      const int hd = c & 2047;
      const int h = hd >> 7, d = hd & 127;
      const float* bp = which == 0 ? b0 : which == 1 ? b1 : b2;
      const float bv = bp[hd];
      if (which == 2) {
        #pragma unroll
        for (int i = 0; i < 4; ++i) {
          const int row0 = m0 + wm + i * 16 + lq * 4;
          const int bb = row0 >> 11, s0 = row0 & 2047;
          u16x4 pv;
          #pragma unroll
          for (int r = 0; r < 4; ++r) pv[r] = f2bf(acc[i][j][r] + bv);
          *(u16x4*)((unsigned short*)o2 + ((size_t)((bb * 16 + h) * 128 + d)) * 2048 + s0) = pv;
        }
      } else {
        const float sc = which == 0 ? QSC : 1.0f;
        unsigned short* op = which == 0 ? (unsigned short*)o0 : (unsigned short*)o1;
        #pragma unroll
        for (int i = 0; i < 4; ++i) {
          #pragma unroll
          for (int r = 0; r < 4; ++r) {
            const int row = m0 + wm + i * 16 + lq * 4 + r;
            const int bb = row >> 11, s = row & 2047;
            op[(size_t)((bb * 16 + h) * 2048 + s) * 128 + d] = f2bf((acc[i][j][r] + bv) * sc);
          }
        }
      }
    } else {
      const float bv = b0[c];
      #pragma unroll
      for (int i = 0; i < 4; ++i)
        #pragma unroll
        for (int r = 0; r < 4; ++r) {
          const int row = m0 + wm + i * 16 + lq * 4 + r;
          ((float*)o0)[(size_t)row * 2048 + c] = acc[i][j][r] + bv;
        }
    }
  }
}

// ---------------- flash attention, causal, transposed softmax ----------------
// grid (32, 32), 256 thr, jq = 31-blockIdx.x (longest first). Each wave owns
// 16 q rows (lane&15 = q). S^T = MFMA(K, Q): k-reduction = regs + 2 shfls.
// O^T = MFMA(V^T, P). Q pre-scaled (QSC) -> scores already in exp2 domain.
__global__ __launch_bounds__(256, 4) void attn(
    const unsigned short* __restrict__ Q,
    const unsigned short* __restrict__ K,
    const unsigned short* __restrict__ Vt,
    unsigned short* __restrict__ ctx) {
  __shared__ unsigned short Ks[64 * 128];   // [kr][dgrp^(kr&15)]  16 KB
  __shared__ unsigned short Vts[128 * 64];  // [d][kgrp^(d&7)]     16 KB
  __shared__ unsigned short Ps[64 * 64];    // [q][kqgrp swizzled]  8 KB

  const int jq = 31 - (int)blockIdx.x;
  const int q0 = jq * 64;
  const int bh = blockIdx.y;
  const int b = bh >> 4, h = bh & 15;
  const unsigned short* Qh = Q + (size_t)bh * 2048 * 128;
  const unsigned short* Kh = K + (size_t)bh * 2048 * 128;
  const unsigned short* Vth = Vt + (size_t)bh * 128 * 2048;

  const int tid = threadIdx.x;
  const int wave = tid >> 6, lid = tid & 63;
  const int l16 = lid & 15, lq = lid >> 4;
  const int wq = wave * 16;
  const int ql = wq + l16;          // this lane's local q row
  const int qrow = q0 + ql;         // global q row
  const int sw = 2 * (l16 & 7);     // Ps swizzle mask

  // Q fragments (B-operand): B[n=l16 (q)][k=d]
  bf16x8 qf[4];
  #pragma unroll
  for (int kc = 0; kc < 4; ++kc)
    qf[kc] = *(const bf16x8*)(Qh + (size_t)qrow * 128 + kc * 32 + lq * 8);

  float m_i = -1e30f, l_i = 0.f;
  f32x4 acc[8] = {};  // O^T: acc[dm], col=l16 (q), row=lq*4+r -> d=dm*16+lq*4+r

  for (int jt = 0; jt <= jq; ++jt) {
    const int k0 = jt * 64;
    #pragma unroll
    for (int ii = 0; ii < 4; ++ii) {  // K tile 16 KB
      const int t = wave * 4 + ii;
      const int r = t * 4 + lq;
      const int g = l16 ^ (r & 15);
      gll16(Kh + (size_t)(k0 + r) * 128 + g * 8, (char*)Ks + t * 1024 + lid * 16);
    }
    #pragma unroll
    for (int ii = 0; ii < 4; ++ii) {  // Vt tile 16 KB (already [d][s])
      const int t = wave * 4 + ii;
      const int d = t * 8 + (lid >> 3);
      const int g = (lid & 7) ^ (d & 7);
      gll16(Vth + (size_t)d * 2048 + k0 + g * 8, (char*)Vts + t * 1024 + lid * 16);
    }
    __syncthreads();

    // S^T = K Q^T: A=K-frag, B=Q-frag. sacc[km]: row=k, col=q
    f32x4 sacc[4] = {};
    #pragma unroll
    for (int kc = 0; kc < 4; ++kc) {
      #pragma unroll
      for (int km = 0; km < 4; ++km) {
        bf16x8 af = *(const bf16x8*)(Ks + (km * 16 + l16) * 128 + (((kc * 4 + lq) ^ l16) << 3));
        sacc[km] = MFMA16(af, qf[kc], sacc[km]);
      }
    }

    if (jt == jq) {  // diagonal tile: causal mask
      #pragma unroll
      for (int km = 0; km < 4; ++km)
        #pragma unroll
        for (int r = 0; r < 4; ++r)
          if (k0 + km * 16 + lq * 4 + r > qrow) sacc[km][r] = -1e30f;
    }

    float tmax = -1e30f;
    #pragma unroll
    for (int km = 0; km < 4; ++km)
      #pragma unroll
      for (int r = 0; r < 4; ++r) tmax = fmaxf(tmax, sacc[km][r]);
    tmax = fmaxf(tmax, __shfl_xor(tmax, 16));
    tmax = fmaxf(tmax, __shfl_xor(tmax, 32));

    const float mnew = fmaxf(m_i, tmax);
    const float alpha = exp2f(m_i - mnew);
    m_i = mnew;

    float ps = 0.f;
    u16x4 pk[4];
    #pragma unroll
    for (int km = 0; km < 4; ++km) {
      #pragma unroll
      for (int r = 0; r < 4; ++r) {
        const float p = exp2f(sacc[km][r] - mnew);
        ps += p;
        pk[km][r] = f2bf(p);
      }
    }
    ps += __shfl_xor(ps, 16);
    ps += __shfl_xor(ps, 32);
    l_i = l_i * alpha + ps;
    #pragma unroll
    for (int dm = 0; dm < 8; ++dm) acc[dm] *= alpha;

    // P^T -> Ps[q][k], 4-k groups XOR-swizzled (wave-private rows: no barrier)
    #pragma unroll
    for (int km = 0; km < 4; ++km)
      *(u16x4*)(Ps + ql * 64 + ((((km * 4) + lq) ^ sw) << 2)) = pk[km];

    // O^T += V^T P^T: A=V^T-frag, B=P-frag
    #pragma unroll
    for (int kc = 0; kc < 2; ++kc) {
      const int G = kc * 4 + lq;
      const int pg = (kc * 8 + 2 * lq) ^ sw;  // even -> 16B aligned
      bf16x8 pf = *(const bf16x8*)(Ps + ql * 64 + (pg << 2));
      #pragma unroll
      for (int dm = 0; dm < 8; ++dm) {
        bf16x8 vf = *(const bf16x8*)(Vts + (dm * 16 + l16) * 64 + ((G ^ (l16 & 7)) << 3));
        acc[dm] = MFMA16(vf, pf, acc[dm]);
      }
    }
    __syncthreads();
  }

  // epilogue: ctx[b][s][h*128+d], 8B packed stores
  const float inv = 1.f / l_i;
  const size_t base = ((size_t)(b * 2048 + qrow)) * 2048 + h * 128;
  #pragma unroll
  for (int dm = 0; dm < 8; ++dm) {
    u16x4 o;
    #pragma unroll
    for (int r = 0; r < 4; ++r) o[r] = f2bf(acc[dm][r] * inv);
    *(u16x4*)(ctx + base + dm * 16 + lq * 4) = o;
  }
}

// ---------------- launch ----------------
extern "C" void kernel_launch(void* const* d_in, const int* in_sizes, int n_in,
                              void* d_out, int out_size, void* d_ws, size_t ws_size,
                              hipStream_t stream) {
  const float* hs = (const float*)d_in[0];
  const float* Wq = (const float*)d_in[1];
  const float* bq = (const float*)d_in[2];
  const float* Wk = (const float*)d_in[3];
  const float* bk = (const float*)d_in[4];
  const float* Wv = (const float*)d_in[5];
  const float* bv = (const float*)d_in[6];
  const float* Wo = (const float*)d_in[7];
  const float* bo = (const float*)d_in[8];
  // d_in[9] = causal_mask (standard causal; computed analytically in attn)
  float* out = (float*)d_out;

  char* ws = (char*)d_ws;
  unsigned short* hsb   = (unsigned short*)(ws);              // 16 MB [4096][2048]
  unsigned short* wqkvt = (unsigned short*)(ws + (16 << 20)); // 24 MB [6144][2048]
  unsigned short* wot   = (unsigned short*)(ws + (40 << 20)); //  8 MB
  unsigned short* Qb    = (unsigned short*)(ws + (48 << 20)); // 16 MB [bh][s][d]
  unsigned short* Kb    = (unsigned short*)(ws + (64 << 20)); // 16 MB [bh][s][d]
  unsigned short* Vtb   = (unsigned short*)(ws + (80 << 20)); // 16 MB [bh][d][s]
  unsigned short* ctx   = (unsigned short*)(ws + (96 << 20)); // 16 MB [4096][2048]

  cvt_bf16<<<dim3(8192), dim3(256), 0, stream>>>(hs, hsb);
  transpose_cvt4<<<dim3(64, 64, 4), dim3(32, 8), 0, stream>>>(Wq, Wk, Wv, Wo, wqkvt, wot);

  gemm128<1><<<dim3(48, 32), 256, 0, stream>>>(hsb, wqkvt, bq, bk, bv,
                                               (void*)Qb, (void*)Kb, (void*)Vtb);
  attn<<<dim3(32, 32), 256, 0, stream>>>(Qb, Kb, Vtb, ctx);
  gemm128<0><<<dim3(16, 32), 256, 0, stream>>>(ctx, wot, bo, nullptr, nullptr,
                                               (void*)out, nullptr, nullptr);
}

// Round 4
// 380.050 us; speedup vs baseline: 1.3278x; 1.0801x over previous
//
#include <hip/hip_runtime.h>
#include <cstdint>

typedef __attribute__((ext_vector_type(4))) float f32x4;
typedef __attribute__((ext_vector_type(16))) float f32x16;
typedef __attribute__((ext_vector_type(8))) __bf16 bf16x8;
typedef __attribute__((ext_vector_type(4))) unsigned short u16x4;
typedef __attribute__((ext_vector_type(2))) unsigned int u32x2;
typedef __attribute__((ext_vector_type(4))) float fvec4;

#define DEV __device__ __forceinline__
#define MFMA16(a, b, c) __builtin_amdgcn_mfma_f32_16x16x32_bf16((a), (b), (c), 0, 0, 0)
#define MFMA32(a, b, c) __builtin_amdgcn_mfma_f32_32x32x16_bf16((a), (b), (c), 0, 0, 0)

// RNE float -> bf16
DEV unsigned short f2bf(float f) {
  union { float f; uint32_t u; } c; c.f = f;
  uint32_t u = c.u;
  return (unsigned short)((u + 0x7FFFu + ((u >> 16) & 1u)) >> 16);
}

// pack two floats to 2 bf16 in one dword (round-half-up, 3 VALU ops)
DEV unsigned int pack2(float lo, float hi) {
  union { float f; uint32_t u; } a, b;
  a.f = lo; b.f = hi;
  return __builtin_amdgcn_perm(b.u + 0x8000u, a.u + 0x8000u, 0x07060302u);
}

// async global->LDS, 16B/lane; LDS dest = wave-uniform base + lane*16
DEV void gll16(const void* g, void* l) {
  __builtin_amdgcn_global_load_lds(
      (const __attribute__((address_space(1))) void*)(uintptr_t)g,
      (__attribute__((address_space(3))) void*)(uint32_t)(uintptr_t)l,
      16, 0, 0);
}

// ---------------- elementwise fp32 -> bf16 ----------------
__global__ void cvt_bf16(const float* __restrict__ src, unsigned short* __restrict__ dst) {
  int i = (blockIdx.x * 256 + threadIdx.x) * 4;
  fvec4 v = *(const fvec4*)(src + i);
  u16x4 o;
  o[0] = f2bf(v[0]); o[1] = f2bf(v[1]); o[2] = f2bf(v[2]); o[3] = f2bf(v[3]);
  *(u16x4*)(dst + i) = o;
}

// ---------------- 4x fused: W [K][N] fp32 -> WT [N][K] bf16 ----------------
__global__ void transpose_cvt4(const float* __restrict__ W0, const float* __restrict__ W1,
                               const float* __restrict__ W2, const float* __restrict__ W3,
                               unsigned short* __restrict__ Dqkv, unsigned short* __restrict__ Do) {
  __shared__ float t[32][33];
  const float* W = blockIdx.z == 0 ? W0 : blockIdx.z == 1 ? W1 : blockIdx.z == 2 ? W2 : W3;
  unsigned short* WT = blockIdx.z < 3 ? Dqkv + (size_t)blockIdx.z * 2048 * 2048 : Do;
  int n0 = blockIdx.x * 32, k0 = blockIdx.y * 32;
  int x = threadIdx.x, y = threadIdx.y;  // block (32,8)
  #pragma unroll
  for (int i = 0; i < 32; i += 8)
    t[y + i][x] = W[(size_t)(k0 + y + i) * 2048 + n0 + x];
  __syncthreads();
  #pragma unroll
  for (int i = 0; i < 32; i += 8)
    WT[(size_t)(n0 + y + i) * 2048 + k0 + x] = f2bf(t[x][y + i]);
}

// softmax scale folded into Q (exp2 domain): rsqrt(DH)*log2(e)
constexpr float QSC = 0.08838834764831845f * 1.4426950408889634f;

// ---------------- 128x128-tile GEMM, flat grid + XCD swizzle ----------------
// mt = (id&7)*4 + ((id>>3)&3), nt = id>>5  ->  each XCD L2 caches a 2MB A-slice.
// MODE 0: C = A@Bt^T + b0 -> fp32 o0 [4096][2048]
// MODE 1: fused QKV (N=6144): Q (scaled QSC)/K -> [bh][s][d] bf16; V -> Vt[bh][d][s]
template <int MODE>
__global__ __launch_bounds__(256, 2) void gemm128(
    const unsigned short* __restrict__ A,
    const unsigned short* __restrict__ Bt,
    const float* __restrict__ b0, const float* __restrict__ b1,
    const float* __restrict__ b2,
    void* __restrict__ o0, void* __restrict__ o1, void* __restrict__ o2) {
  __shared__ unsigned short As[128 * 64];
  __shared__ unsigned short Bs[128 * 64];
  const int id = blockIdx.x;
  const int m0 = (((id & 7) << 2) | ((id >> 3) & 3)) * 128;
  const int n0 = (id >> 5) * 128;
  const int tid = threadIdx.x;
  const int wave = tid >> 6, lid = tid & 63;
  const int l16 = lid & 15, lq = lid >> 4;
  const int wm = (wave >> 1) * 64, wn = (wave & 1) * 64;

  const int srow = lid >> 3;
  const int sgrp = (lid & 7) ^ srow;

  f32x4 acc[4][4] = {};

  for (int k0 = 0; k0 < 2048; k0 += 64) {
    #pragma unroll
    for (int i = 0; i < 4; ++i) {
      const int t = wave * 4 + i;
      const int r = t * 8 + srow;
      gll16(A + (size_t)(m0 + r) * 2048 + k0 + sgrp * 8, (char*)As + t * 1024 + lid * 16);
      gll16(Bt + (size_t)(n0 + r) * 2048 + k0 + sgrp * 8, (char*)Bs + t * 1024 + lid * 16);
    }
    __syncthreads();
    #pragma unroll
    for (int kk = 0; kk < 2; ++kk) {
      const int G = kk * 4 + lq;
      bf16x8 af[4], bfr[4];
      #pragma unroll
      for (int i = 0; i < 4; ++i)
        af[i] = *(const bf16x8*)(As + (wm + i * 16 + l16) * 64 + ((G ^ (l16 & 7)) << 3));
      #pragma unroll
      for (int j = 0; j < 4; ++j)
        bfr[j] = *(const bf16x8*)(Bs + (wn + j * 16 + l16) * 64 + ((G ^ (l16 & 7)) << 3));
      #pragma unroll
      for (int i = 0; i < 4; ++i)
        #pragma unroll
        for (int j = 0; j < 4; ++j)
          acc[i][j] = MFMA16(af[i], bfr[j], acc[i][j]);
    }
    __syncthreads();
  }

  #pragma unroll
  for (int j = 0; j < 4; ++j) {
    const int c = n0 + wn + j * 16 + l16;
    if (MODE == 1) {
      const int which = c >> 11;  // 0=Q 1=K 2=V
      const int hd = c & 2047;
      const int h = hd >> 7, d = hd & 127;
      const float* bp = which == 0 ? b0 : which == 1 ? b1 : b2;
      const float bv = bp[hd];
      if (which == 2) {
        #pragma unroll
        for (int i = 0; i < 4; ++i) {
          const int row0 = m0 + wm + i * 16 + lq * 4;
          const int bb = row0 >> 11, s0 = row0 & 2047;
          u16x4 pv;
          #pragma unroll
          for (int r = 0; r < 4; ++r) pv[r] = f2bf(acc[i][j][r] + bv);
          *(u16x4*)((unsigned short*)o2 + ((size_t)((bb * 16 + h) * 128 + d)) * 2048 + s0) = pv;
        }
      } else {
        const float sc = which == 0 ? QSC : 1.0f;
        unsigned short* op = which == 0 ? (unsigned short*)o0 : (unsigned short*)o1;
        #pragma unroll
        for (int i = 0; i < 4; ++i) {
          #pragma unroll
          for (int r = 0; r < 4; ++r) {
            const int row = m0 + wm + i * 16 + lq * 4 + r;
            const int bb = row >> 11, s = row & 2047;
            op[(size_t)((bb * 16 + h) * 2048 + s) * 128 + d] = f2bf((acc[i][j][r] + bv) * sc);
          }
        }
      }
    } else {
      const float bv = b0[c];
      #pragma unroll
      for (int i = 0; i < 4; ++i)
        #pragma unroll
        for (int r = 0; r < 4; ++r) {
          const int row = m0 + wm + i * 16 + lq * 4 + r;
          ((float*)o0)[(size_t)row * 2048 + c] = acc[i][j][r] + bv;
        }
    }
  }
}

// ---------------- flash attention: 32x32x16 MFMA, 128-q blocks ----------------
// grid (16,32). jq = (bh<16) ? 15-x : x  -> CU pairs (id, id+256) sum to 34
// k-tile-units: uniform per-CU work. Wave owns 32 q (q = lane&31); S^T/O^T in
// 32x32 C-layout: col=lane&31, row=(reg&3)+8*(reg>>2)+4*(lane>>5).
__global__ __launch_bounds__(256, 2) void attn(
    const unsigned short* __restrict__ Q,
    const unsigned short* __restrict__ K,
    const unsigned short* __restrict__ Vt,
    unsigned short* __restrict__ ctx) {
  __shared__ unsigned short Ks[64 * 128];      // [kr][16B-chunk ^ (kr&15)] 16KB
  __shared__ unsigned short Vts[128 * 64];     // [d][16B-chunk ^ (d&7)]    16KB
  __shared__ unsigned short Ps[4 * 32 * 64];   // per-wave [q][chunk ^ (q&7)] 16KB

  const int bh = blockIdx.y;
  const int jq = (bh < 16) ? (15 - (int)blockIdx.x) : (int)blockIdx.x;
  const int q0 = jq * 128;
  const int b = bh >> 4, h = bh & 15;
  const unsigned short* Qh = Q + (size_t)bh * 2048 * 128;
  const unsigned short* Kh = K + (size_t)bh * 2048 * 128;
  const unsigned short* Vth = Vt + (size_t)bh * 128 * 2048;

  const int tid = threadIdx.x;
  const int wave = tid >> 6, lid = tid & 63;
  const int l32 = lid & 31, half = lid >> 5;
  const int qrow = q0 + wave * 32 + l32;  // this lane's global q row
  unsigned short* Pw = Ps + wave * 2048 + l32 * 64;  // this lane's P row
  const int qsw = l32 & 7;

  // Q fragments (B-operand): B[k=d][n=q], per dstep 16 d
  bf16x8 qf[8];
  #pragma unroll
  for (int ds = 0; ds < 8; ++ds)
    qf[ds] = *(const bf16x8*)(Qh + (size_t)qrow * 128 + ds * 16 + half * 8);

  float m_i = -1e30f, l_i = 0.f;
  f32x16 acc[4] = {};  // O^T: acc[dblk], d = dblk*32 + (reg&3)+8*(reg>>2)+4*half

  const int ntiles = 2 * jq + 2;
  for (int jt = 0; jt < ntiles; ++jt) {
    const int k0 = jt * 64;
    #pragma unroll
    for (int ii = 0; ii < 4; ++ii) {  // K tile 16KB: 4 rows x 256B per call
      const int t = wave * 4 + ii;
      const int r = t * 4 + (lid >> 4);
      const int g = (lid & 15) ^ (r & 15);
      gll16(Kh + (size_t)(k0 + r) * 128 + g * 8, (char*)Ks + t * 1024 + lid * 16);
    }
    #pragma unroll
    for (int ii = 0; ii < 4; ++ii) {  // Vt tile 16KB: 8 rows x 128B per call
      const int t = wave * 4 + ii;
      const int d = t * 8 + (lid >> 3);
      const int g = (lid & 7) ^ (d & 7);
      gll16(Vth + (size_t)d * 2048 + k0 + g * 8, (char*)Vts + t * 1024 + lid * 16);
    }
    __syncthreads();

    // S^T = K Q^T: A=K-frag (m=k-row), B=Q-frag (n=q)
    f32x16 sacc[2] = {};
    #pragma unroll
    for (int ds = 0; ds < 8; ++ds) {
      #pragma unroll
      for (int mb = 0; mb < 2; ++mb) {
        const int kr = mb * 32 + l32;
        bf16x8 af = *(const bf16x8*)(Ks + kr * 128 + (((ds * 2 + half) ^ (kr & 15)) << 3));
        sacc[mb] = MFMA32(af, qf[ds], sacc[mb]);
      }
    }

    if (jt >= 2 * jq) {  // only the last two tiles touch the diagonal
      #pragma unroll
      for (int mb = 0; mb < 2; ++mb)
        #pragma unroll
        for (int i = 0; i < 16; ++i) {
          const int kg = k0 + mb * 32 + (i & 3) + 8 * (i >> 2) + 4 * half;
          if (kg > qrow) sacc[mb][i] = -1e30f;
        }
    }

    float tmax = -1e30f;
    #pragma unroll
    for (int mb = 0; mb < 2; ++mb)
      #pragma unroll
      for (int i = 0; i < 16; ++i) tmax = fmaxf(tmax, sacc[mb][i]);
    tmax = fmaxf(tmax, __shfl_xor(tmax, 32));

    const float mnew = fmaxf(m_i, tmax);
    const float alpha = exp2f(m_i - mnew);
    m_i = mnew;

    float ps = 0.f;
    #pragma unroll
    for (int mb = 0; mb < 2; ++mb) {
      #pragma unroll
      for (int i = 0; i < 16; ++i) {
        sacc[mb][i] = exp2f(sacc[mb][i] - mnew);
        ps += sacc[mb][i];
      }
      // store P^T: chunk u covers k = mb*32 + 8u + 4*half + {0..3}
      #pragma unroll
      for (int u = 0; u < 4; ++u) {
        u32x2 w;
        w[0] = pack2(sacc[mb][4 * u], sacc[mb][4 * u + 1]);
        w[1] = pack2(sacc[mb][4 * u + 2], sacc[mb][4 * u + 3]);
        *(u32x2*)(Pw + (((u + mb * 4) ^ qsw) << 3) + half * 4) = w;
      }
    }
    ps += __shfl_xor(ps, 32);
    l_i = l_i * alpha + ps;
    #pragma unroll
    for (int db = 0; db < 4; ++db)
      #pragma unroll
      for (int i = 0; i < 16; ++i) acc[db][i] *= alpha;

    // O^T += V^T P^T: A=V^T-frag (m=d), B=P-frag (n=q)
    #pragma unroll
    for (int ks = 0; ks < 4; ++ks) {
      bf16x8 pf = *(const bf16x8*)(Pw + (((ks * 2 + half) ^ qsw) << 3));
      #pragma unroll
      for (int db = 0; db < 4; ++db) {
        const int d = db * 32 + l32;
        bf16x8 vf = *(const bf16x8*)(Vts + d * 64 + (((ks * 2 + half) ^ (d & 7)) << 3));
        acc[db] = MFMA32(vf, pf, acc[db]);
      }
    }
    __syncthreads();
  }

  // epilogue: ctx[b][s][h*128+d], packed 8B stores
  const float inv = 1.f / l_i;
  const size_t base = ((size_t)(b * 2048 + qrow)) * 2048 + h * 128;
  #pragma unroll
  for (int db = 0; db < 4; ++db) {
    #pragma unroll
    for (int u = 0; u < 4; ++u) {
      u32x2 w;
      w[0] = pack2(acc[db][4 * u] * inv, acc[db][4 * u + 1] * inv);
      w[1] = pack2(acc[db][4 * u + 2] * inv, acc[db][4 * u + 3] * inv);
      *(u32x2*)(ctx + base + db * 32 + 8 * u + 4 * half) = w;
    }
  }
}

// ---------------- launch ----------------
extern "C" void kernel_launch(void* const* d_in, const int* in_sizes, int n_in,
                              void* d_out, int out_size, void* d_ws, size_t ws_size,
                              hipStream_t stream) {
  const float* hs = (const float*)d_in[0];
  const float* Wq = (const float*)d_in[1];
  const float* bq = (const float*)d_in[2];
  const float* Wk = (const float*)d_in[3];
  const float* bk = (const float*)d_in[4];
  const float* Wv = (const float*)d_in[5];
  const float* bv = (const float*)d_in[6];
  const float* Wo = (const float*)d_in[7];
  const float* bo = (const float*)d_in[8];
  // d_in[9] = causal_mask (standard causal; computed analytically in attn)
  float* out = (float*)d_out;

  char* ws = (char*)d_ws;
  unsigned short* hsb   = (unsigned short*)(ws);              // 16 MB [4096][2048]
  unsigned short* wqkvt = (unsigned short*)(ws + (16 << 20)); // 24 MB [6144][2048]
  unsigned short* wot   = (unsigned short*)(ws + (40 << 20)); //  8 MB
  unsigned short* Qb    = (unsigned short*)(ws + (48 << 20)); // 16 MB [bh][s][d]
  unsigned short* Kb    = (unsigned short*)(ws + (64 << 20)); // 16 MB [bh][s][d]
  unsigned short* Vtb   = (unsigned short*)(ws + (80 << 20)); // 16 MB [bh][d][s]
  unsigned short* ctx   = (unsigned short*)(ws + (96 << 20)); // 16 MB [4096][2048]

  cvt_bf16<<<dim3(8192), dim3(256), 0, stream>>>(hs, hsb);
  transpose_cvt4<<<dim3(64, 64, 4), dim3(32, 8), 0, stream>>>(Wq, Wk, Wv, Wo, wqkvt, wot);

  gemm128<1><<<dim3(1536), 256, 0, stream>>>(hsb, wqkvt, bq, bk, bv,
                                             (void*)Qb, (void*)Kb, (void*)Vtb);
  attn<<<dim3(16, 32), 256, 0, stream>>>(Qb, Kb, Vtb, ctx);
  gemm128<0><<<dim3(512), 256, 0, stream>>>(ctx, wot, bo, nullptr, nullptr,
                                            (void*)out, nullptr, nullptr);
}